// Round 12
// baseline (2249.651 us; speedup 1.0000x reference)
//
#include <hip/hip_runtime.h>
#include <hip/hip_bf16.h>
#include <stdint.h>

#define D_VIT 768
#define D_SAE 12288
#define TOPK 32
#define NC 48           // fast-path requires >=48 codes above the check code
#define CMAX 256        // candidate slots per row
#define THETA 3.25f     // encoder emission threshold (mfma-f32 domain)

typedef __attribute__((ext_vector_type(8))) short bf8_t;   // 8 bf16 (4 VGPRs)
typedef __attribute__((ext_vector_type(4))) float f4_t;    // 4 f32 acc
typedef const __attribute__((address_space(1))) void* gas_t;
typedef __attribute__((address_space(3))) void* las_t;

// ---------------- transpose W_enc (768 x 12288) -> wt f32 + wtb bf16 ---------
__global__ void k_transpose(const float* __restrict__ src, float* __restrict__ dst,
                            __hip_bfloat16* __restrict__ dstb) {
    __shared__ float t[32][33];
    int f0 = blockIdx.x * 32, k0 = blockIdx.y * 32;
    int tx = threadIdx.x, ty = threadIdx.y;
#pragma unroll
    for (int j = 0; j < 32; j += 8)
        t[ty + j][tx] = src[(size_t)(k0 + ty + j) * D_SAE + f0 + tx];
    __syncthreads();
#pragma unroll
    for (int j = 0; j < 32; j += 8) {
        float v = t[tx][ty + j];
        dst[(size_t)(f0 + ty + j) * D_VIT + k0 + tx] = v;
        dstb[(size_t)(f0 + ty + j) * D_VIT + k0 + tx] = __float2bfloat16(v);
    }
}

// ---------------- xb = bf16(x - b_dec) ---------------------------------------
__global__ __launch_bounds__(256) void k_cvt_x(const float* __restrict__ x,
    const float* __restrict__ bdec, __hip_bfloat16* __restrict__ xb, long long n) {
    long long i = ((long long)blockIdx.x * 256 + threadIdx.x) * 8;
    if (i >= n) return;
    float4 a = *reinterpret_cast<const float4*>(x + i);
    float4 b = *reinterpret_cast<const float4*>(x + i + 4);
    int kk = (int)(i % D_VIT);
    float4 c = *reinterpret_cast<const float4*>(bdec + kk);
    float4 d = *reinterpret_cast<const float4*>(bdec + kk + 4);
    union { __hip_bfloat16 h[8]; uint4 v; } o;
    o.h[0] = __float2bfloat16(a.x - c.x); o.h[1] = __float2bfloat16(a.y - c.y);
    o.h[2] = __float2bfloat16(a.z - c.z); o.h[3] = __float2bfloat16(a.w - c.w);
    o.h[4] = __float2bfloat16(b.x - d.x); o.h[5] = __float2bfloat16(b.y - d.y);
    o.h[6] = __float2bfloat16(b.z - d.z); o.h[7] = __float2bfloat16(b.w - d.w);
    *reinterpret_cast<uint4*>(xb + i) = o.v;
}

// ---------------- wdecb = bf16(wdec) -----------------------------------------
__global__ __launch_bounds__(256) void k_cvt_w(const float* __restrict__ wdec,
    __hip_bfloat16* __restrict__ wdecb, long long n) {
    long long i = ((long long)blockIdx.x * 256 + threadIdx.x) * 8;
    if (i >= n) return;
    float4 a = *reinterpret_cast<const float4*>(wdec + i);
    float4 b = *reinterpret_cast<const float4*>(wdec + i + 4);
    union { __hip_bfloat16 h[8]; uint4 v; } o;
    o.h[0] = __float2bfloat16(a.x); o.h[1] = __float2bfloat16(a.y);
    o.h[2] = __float2bfloat16(a.z); o.h[3] = __float2bfloat16(a.w);
    o.h[4] = __float2bfloat16(b.x); o.h[5] = __float2bfloat16(b.y);
    o.h[6] = __float2bfloat16(b.z); o.h[7] = __float2bfloat16(b.w);
    *reinterpret_cast<uint4*>(wdecb + i) = o.v;
}

// ---------------- zero per-row counters / flags -------------------------------
__global__ __launch_bounds__(256) void k_zero(int* __restrict__ cnt,
                                              int* __restrict__ fflag, int M) {
    int i = blockIdx.x * 256 + threadIdx.x;
    if (i < M) { cnt[i] = 0; fflag[i] = 0; }
}

// ------- 256x256x64 8-wave dbuf MFMA encoder -> candidate emission only ------
#define GBM 256
#define GBN 256
#define GBK 64
#define NKT (D_VIT / GBK)   // 12

__global__ __launch_bounds__(512, 2) void k_enc8(
    const __hip_bfloat16* __restrict__ xb, const __hip_bfloat16* __restrict__ wtb,
    int* __restrict__ cnt, int* __restrict__ candb, int mrows) {
    __shared__ __hip_bfloat16 lds[2][2][GBM * GBK];   // 128 KiB
    int tid = threadIdx.x;
    int lane = tid & 63, w = tid >> 6;
    int wm = w >> 2, wn = w & 3;                      // 2 x 4 waves
    int tile_m = blockIdx.y * GBM, tile_n = blockIdx.x * GBN;
    int lrow = lane & 15, lk = lane >> 4;
    int G0 = w * 64 + lane;

    f4_t acc[2][4][2][2] = {};                        // [mq][f][nq][g]

    auto STAGE = [&](int kt, int h, int b) {
#pragma unroll
        for (int j = 0; j < 2; ++j) {
            int G = G0 + j * 512;
            int r = G >> 3, s = G & 7;
            int gg = s ^ (r & 7);
            int half = h >> 1;
            if ((h & 1) == 0) {
                int ar = tile_m + half * 128 + r;
                if (ar >= mrows) ar = mrows - 1;
                const __hip_bfloat16* src = xb + (size_t)ar * D_VIT + kt * GBK + gg * 8;
                __builtin_amdgcn_global_load_lds((gas_t)src,
                    (las_t)(&lds[b][0][half * 8192 + (w * 64 + j * 512) * 8]), 16, 0, 0);
            } else {
                int br = tile_n + half * 128 + r;
                const __hip_bfloat16* src = wtb + (size_t)br * D_VIT + kt * GBK + gg * 8;
                __builtin_amdgcn_global_load_lds((gas_t)src,
                    (las_t)(&lds[b][1][half * 8192 + (w * 64 + j * 512) * 8]), 16, 0, 0);
            }
        }
    };

#define PHASE(MQ, NQ, BUF) do {                                                \
        const __hip_bfloat16* Ab = &lds[BUF][0][0];                            \
        const __hip_bfloat16* Bb = &lds[BUF][1][0];                            \
        bf8_t af[4][2], bv[2][2];                                              \
        _Pragma("unroll")                                                      \
        for (int f = 0; f < 4; ++f) {                                          \
            int ra = wm * 128 + (MQ) * 64 + f * 16 + lrow;                     \
            _Pragma("unroll")                                                  \
            for (int h = 0; h < 2; ++h) {                                      \
                int sl = (lk + 4 * h) ^ (ra & 7);                              \
                af[f][h] = *reinterpret_cast<const bf8_t*>(Ab + ra * GBK + sl * 8); \
            }                                                                  \
        }                                                                      \
        _Pragma("unroll")                                                      \
        for (int g = 0; g < 2; ++g) {                                          \
            int rb = wn * 64 + (NQ) * 32 + g * 16 + lrow;                      \
            _Pragma("unroll")                                                  \
            for (int h = 0; h < 2; ++h) {                                      \
                int sl = (lk + 4 * h) ^ (rb & 7);                              \
                bv[g][h] = *reinterpret_cast<const bf8_t*>(Bb + rb * GBK + sl * 8); \
            }                                                                  \
        }                                                                      \
        __builtin_amdgcn_s_setprio(1);                                         \
        _Pragma("unroll")                                                      \
        for (int h = 0; h < 2; ++h)                                            \
            _Pragma("unroll")                                                  \
            for (int f = 0; f < 4; ++f)                                        \
                _Pragma("unroll")                                              \
                for (int g = 0; g < 2; ++g)                                    \
                    acc[MQ][f][NQ][g] = __builtin_amdgcn_mfma_f32_16x16x32_bf16( \
                        bv[g][h], af[f][h], acc[MQ][f][NQ][g], 0, 0, 0);       \
        __builtin_amdgcn_s_setprio(0);                                         \
    } while (0)

#pragma unroll
    for (int h = 0; h < 4; ++h) STAGE(0, h, 0);

    int cur = 0;
#pragma unroll 1
    for (int t = 0; t < NKT; ++t) {
        int nb = cur ^ 1;
        bool pf = (t + 1 < NKT);
        if (pf) STAGE(t + 1, 0, nb);
        if (pf) asm volatile("s_waitcnt vmcnt(2)" ::: "memory");
        else    asm volatile("s_waitcnt vmcnt(0)" ::: "memory");
        __builtin_amdgcn_s_barrier();
        asm volatile("" ::: "memory");
        __builtin_amdgcn_sched_barrier(0);
        PHASE(0, 0, cur);
        if (pf) STAGE(t + 1, 1, nb);
        PHASE(1, 0, cur);
        if (pf) STAGE(t + 1, 2, nb);
        PHASE(0, 1, cur);
        if (pf) STAGE(t + 1, 3, nb);
        PHASE(1, 1, cur);
        asm volatile("" ::: "memory");
        __builtin_amdgcn_s_barrier();
        asm volatile("" ::: "memory");
        cur = nb;
    }
#undef PHASE

    // candidate emission: values >= THETA only; no acts store at all.
#pragma unroll
    for (int mq = 0; mq < 2; ++mq)
#pragma unroll
        for (int f = 0; f < 4; ++f) {
            int xr = tile_m + wm * 128 + mq * 64 + f * 16 + lrow;
            if (xr < mrows) {
#pragma unroll
                for (int nq = 0; nq < 2; ++nq)
#pragma unroll
                    for (int g = 0; g < 2; ++g) {
                        int fb = tile_n + wn * 64 + nq * 32 + g * 16 + lk * 4;
#pragma unroll
                        for (int q = 0; q < 4; ++q) {
                            float r = acc[mq][f][nq][g][q];
                            if (r >= THETA) {
                                int slot = atomicAdd(&cnt[xr], 1);
                                if (slot < CMAX) {
                                    union { __hip_bfloat16 h; unsigned short u; } cc;
                                    cc.h = __float2bfloat16(r);
                                    candb[(size_t)xr * CMAX + slot] =
                                        (int)(((unsigned)cc.u << 16) | (unsigned)(fb + q));
                                }
                            }
                        }
                    }
            }
        }
}

// -------- per-row select: candidate list -> band f64 rerank -> decode --------
__global__ __launch_bounds__(256) void k_select(
    const int* __restrict__ cnt, const int* __restrict__ candb,
    const float* __restrict__ x, const float* __restrict__ bdec,
    const float* __restrict__ wt, const __hip_bfloat16* __restrict__ wdecb,
    float* __restrict__ out, int* __restrict__ fflag) {
    int row = blockIdx.x, tid = threadIdx.x;

    __shared__ float xs[D_VIT];
    __shared__ int cand[CMAX];
    __shared__ float cvfin[CMAX];
    __shared__ float cexact[CMAX];
    __shared__ unsigned char cflag[CMAX];
    __shared__ short alist[CMAX];
    __shared__ float sval[TOPK];
    __shared__ int sidx[TOPK];
    __shared__ int s_nq, s_na, s_nd;
    __shared__ float s_vb;

    if (tid < CMAX) cflag[tid] = 0;
    if (tid < TOPK) { sval[tid] = 0.f; sidx[tid] = 0; }
    if (tid == 0) { s_nq = 0; s_na = 0; s_nd = 0; s_vb = 0.f; }
    for (int i = tid; i < D_VIT; i += 256)
        xs[i] = x[(size_t)row * D_VIT + i] - bdec[i];
    int C0 = cnt[row];
    int C = C0 < CMAX ? C0 : CMAX;
    if (tid < C) cand[tid] = candb[(size_t)row * CMAX + tid];
    __syncthreads();

    // fast-path predicate: >=NC candidates with code >= bf16(3.33).
    // Then every non-candidate (mfma-f32 < THETA, exact < THETA+0.02) is
    // provably outside the top-32 (32nd candidate exact >= 3.3203-0.036).
    unsigned short CQ;
    { union { __hip_bfloat16 h; unsigned short u; } t2; t2.h = __float2bfloat16(3.33f); CQ = t2.u; }
    if (tid < C && ((unsigned)cand[tid] >> 16) >= (unsigned)CQ) atomicAdd(&s_nq, 1);
    __syncthreads();
    if (C0 > CMAX || s_nq < NC) {        // deterministic (C0, set membership)
        if (tid == 0) fflag[row] = 1;    // exact fallback kernel handles row
        return;
    }

    // vb = 32nd-largest code (index tiebreak)
    int myidx = 0; float myval = 0.f;
    if (tid < C) {
        unsigned pk = (unsigned)cand[tid];
        unsigned mc = pk >> 16; myidx = (int)(pk & 0xffffu);
        myval = __uint_as_float(mc << 16);
        int r2 = 0;
        for (int j = 0; j < C; ++j) {
            unsigned pj = (unsigned)cand[j];
            unsigned cj = pj >> 16; int ij = (int)(pj & 0xffffu);
            r2 += (cj > mc) || (cj == mc && ij < myidx);
        }
        if (r2 == 31) s_vb = myval;
    }
    __syncthreads();

    // partition: definite-in / ambiguous band / excluded
    if (tid < C) {
        float vb = s_vb, band = 0.025f + 0.018f * vb;
        if (myval > vb + band) { cflag[tid] = 2; cvfin[tid] = myval; atomicAdd(&s_nd, 1); }
        else if (myval >= vb - band) { int a = atomicAdd(&s_na, 1); alist[a] = (short)tid; cflag[tid] = 1; }
    }
    __syncthreads();
    int na = s_na, nd = s_nd;

    // f64 rerank of band only: 8 cands x 32 threads
    for (int base = 0; base < na; base += 8) {
        int ai = base + (tid >> 5), sub = tid & 31;
        if (ai < na) {
            int c = alist[ai];
            int f = (int)(((unsigned)cand[c]) & 0xffffu);
            const float* wr = wt + (size_t)f * D_VIT;
            double acc = 0.0;
            for (int k = sub * 4; k < D_VIT; k += 128) {
                float4 wv = *reinterpret_cast<const float4*>(wr + k);
                float4 xv = *reinterpret_cast<const float4*>(xs + k);
                acc += (double)wv.x * xv.x + (double)wv.y * xv.y
                     + (double)wv.z * xv.z + (double)wv.w * xv.w;
            }
            acc += __shfl_xor(acc, 1);  acc += __shfl_xor(acc, 2);
            acc += __shfl_xor(acc, 4);  acc += __shfl_xor(acc, 8);
            acc += __shfl_xor(acc, 16);
            if (sub == 0) cexact[c] = (float)(acc > 0.0 ? acc : 0.0);
        }
    }
    __syncthreads();

    // choose top (32-nd) of the band by exact value
    if (tid < C && cflag[tid] == 1) {
        int kq = TOPK - nd;
        float ex = cexact[tid]; int rA = 0;
        for (int j = 0; j < na; ++j) {
            int cj = alist[j];
            float ej = cexact[cj]; int ij = (int)(((unsigned)cand[cj]) & 0xffffu);
            rA += (ej > ex) || (ej == ex && ij < myidx);
        }
        if (rA < kq) { cflag[tid] = 3; cvfin[tid] = ex; }
    }
    __syncthreads();

    // deterministic slot routing among the chosen (content-based)
    if (tid < C && cflag[tid] >= 2) {
        float mv = cvfin[tid]; int rk = 0;
        for (int j = 0; j < C; ++j) {
            if (cflag[j] >= 2) {
                float vj = cvfin[j]; int ij = (int)(((unsigned)cand[j]) & 0xffffu);
                rk += (vj > mv) || (vj == mv && ij < myidx);
            }
        }
        if (rk < TOPK) { sval[rk] = mv; sidx[rk] = myidx; }
    }
    __syncthreads();

    // sparse decode from bf16 wdec + b_dec; nt store
    for (int d = tid; d < D_VIT; d += 256) {
        float o = bdec[d];
#pragma unroll
        for (int j = 0; j < TOPK; j++)
            o = fmaf(sval[j], __bfloat162float(wdecb[(size_t)sidx[j] * D_VIT + d]), o);
        __builtin_nontemporal_store(o, out + (size_t)row * D_VIT + d);
    }
}

// -------- exact fallback for flagged rows (rare; correctness guarantee) ------
__global__ __launch_bounds__(256) void k_fallback(
    const int* __restrict__ fflag, const float* __restrict__ x,
    const float* __restrict__ bdec, const float* __restrict__ wt,
    const __hip_bfloat16* __restrict__ wdecb, float* __restrict__ out, int M) {
    __shared__ float xs[D_VIT];
    __shared__ int cand[64];
    __shared__ double cval[64];
    __shared__ unsigned long long red[4];
    __shared__ float sval[TOPK];
    __shared__ int sidx[TOPK];
    int tid = threadIdx.x;

    for (int row = blockIdx.x; row < M; row += gridDim.x) {
        if (!fflag[row]) continue;   // block-uniform
        for (int i = tid; i < D_VIT; i += 256)
            xs[i] = x[(size_t)row * D_VIT + i] - bdec[i];
        __syncthreads();

        float av[48];                // f32 recompute of the full row (48*256=12288)
        for (int s = 0; s < 48; ++s) {
            int f = tid + 256 * s;
            const float* wr = wt + (size_t)f * D_VIT;
            float a = 0.f;
            for (int k = 0; k < D_VIT; k += 4) {
                float4 wv = *reinterpret_cast<const float4*>(wr + k);
                float4 xv = *reinterpret_cast<const float4*>(xs + k);
                a = fmaf(wv.x, xv.x, a); a = fmaf(wv.y, xv.y, a);
                a = fmaf(wv.z, xv.z, a); a = fmaf(wv.w, xv.w, a);
            }
            av[s] = fmaxf(a, 0.f);
        }
        unsigned long long dead = 0ull;
        for (int it = 0; it < 64; ++it) {     // top-64 superset (f32 margin huge)
            float best = -1.f; int bs = 0;
#pragma unroll
            for (int s = 0; s < 48; ++s) {
                float xv = ((dead >> s) & 1ull) ? -1.f : av[s];
                if (xv > best) { best = xv; bs = s; }
            }
            unsigned fb2 = best >= 0.f ? __float_as_uint(best) : 0u;
            unsigned fl = (unsigned)(bs * 256 + tid);
            unsigned long long p = ((unsigned long long)fb2 << 32)
                                 | (unsigned long long)(0xFFFFFFFFu - fl);
#pragma unroll
            for (int o = 1; o < 64; o <<= 1) {
                unsigned long long q = __shfl_xor(p, o);
                p = p > q ? p : q;
            }
            if ((tid & 63) == 0) red[tid >> 6] = p;
            __syncthreads();
            unsigned long long pm = red[0];
            if (red[1] > pm) pm = red[1];
            if (red[2] > pm) pm = red[2];
            if (red[3] > pm) pm = red[3];
            unsigned fidx = 0xFFFFFFFFu - (unsigned)(pm & 0xFFFFFFFFull);
            if (tid == (int)(fidx & 255u)) dead |= (1ull << (fidx >> 8));
            if (tid == 0) cand[it] = (int)fidx;
            __syncthreads();
        }
        // exact f64 for all 64, then exact top-32 routing
        for (int base = 0; base < 64; base += 8) {
            int ai = base + (tid >> 5), sub = tid & 31;
            int f = cand[ai];
            const float* wr = wt + (size_t)f * D_VIT;
            double a = 0.0;
            for (int k = sub * 4; k < D_VIT; k += 128) {
                float4 wv = *reinterpret_cast<const float4*>(wr + k);
                float4 xv = *reinterpret_cast<const float4*>(xs + k);
                a += (double)wv.x * xv.x + (double)wv.y * xv.y
                   + (double)wv.z * xv.z + (double)wv.w * xv.w;
            }
            a += __shfl_xor(a, 1);  a += __shfl_xor(a, 2);
            a += __shfl_xor(a, 4);  a += __shfl_xor(a, 8);
            a += __shfl_xor(a, 16);
            if (sub == 0) cval[ai] = a > 0.0 ? a : 0.0;
        }
        __syncthreads();
        if (tid < 64) {
            double mv = cval[tid]; int mi = cand[tid]; int rk = 0;
            for (int j = 0; j < 64; ++j) {
                double vj = cval[j]; int ij = cand[j];
                rk += (vj > mv) || (vj == mv && ij < mi);
            }
            if (rk < TOPK) { sval[rk] = (float)mv; sidx[rk] = mi; }
        }
        __syncthreads();
        for (int d = tid; d < D_VIT; d += 256) {
            float o = bdec[d];
#pragma unroll
            for (int j = 0; j < TOPK; j++)
                o = fmaf(sval[j], __bfloat162float(wdecb[(size_t)sidx[j] * D_VIT + d]), o);
            out[(size_t)row * D_VIT + d] = o;
        }
        __syncthreads();
    }
}

extern "C" void kernel_launch(void* const* d_in, const int* in_sizes, int n_in,
                              void* d_out, int out_size, void* d_ws, size_t ws_size,
                              hipStream_t stream) {
    const float* x    = (const float*)d_in[0];
    const float* wenc = (const float*)d_in[1];
    const float* wdec = (const float*)d_in[2];
    const float* bdec = (const float*)d_in[3];
    float* out = (float*)d_out;
    int M = in_sizes[0] / D_VIT;

    size_t wt_b    = (size_t)D_SAE * D_VIT * sizeof(float);
    size_t wtb_b   = (size_t)D_SAE * D_VIT * sizeof(__hip_bfloat16);
    size_t xb_b    = (size_t)M * D_VIT * sizeof(__hip_bfloat16);
    size_t wdecb_b = (size_t)D_SAE * D_VIT * sizeof(__hip_bfloat16);
    size_t cnt_b   = (size_t)M * sizeof(int);
    size_t flag_b  = (size_t)M * sizeof(int);

    char* p = (char*)d_ws;
    float* wt             = (float*)p;              p += wt_b;
    __hip_bfloat16* wtb   = (__hip_bfloat16*)p;     p += wtb_b;
    __hip_bfloat16* xb    = (__hip_bfloat16*)p;     p += xb_b;
    __hip_bfloat16* wdecb = (__hip_bfloat16*)p;     p += wdecb_b;
    int* cnt              = (int*)p;                p += cnt_b;
    int* fflag            = (int*)p;                p += flag_b;
    int* candb            = (int*)p;

    {
        int blocks = (M + 255) / 256;
        hipLaunchKernelGGL(k_zero, dim3(blocks), dim3(256), 0, stream, cnt, fflag, M);
    }
    {
        dim3 g(D_SAE / 32, D_VIT / 32), b(32, 8);
        hipLaunchKernelGGL(k_transpose, g, b, 0, stream, wenc, wt, wtb);
    }
    {
        long long n = (long long)M * D_VIT;
        int blocks = (int)((n / 8 + 255) / 256);
        hipLaunchKernelGGL(k_cvt_x, dim3(blocks), dim3(256), 0, stream, x, bdec, xb, n);
    }
    {
        long long n = (long long)D_SAE * D_VIT;
        int blocks = (int)((n / 8 + 255) / 256);
        hipLaunchKernelGGL(k_cvt_w, dim3(blocks), dim3(256), 0, stream, wdec, wdecb, n);
    }
    {
        dim3 ge(D_SAE / GBN, (M + GBM - 1) / GBM), be(512);
        hipLaunchKernelGGL(k_enc8, ge, be, 0, stream, xb, wtb, cnt, candb, M);
    }
    hipLaunchKernelGGL(k_select, dim3(M), dim3(256), 0, stream,
                       cnt, candb, x, bdec, wt, wdecb, out, fflag);
    hipLaunchKernelGGL(k_fallback, dim3(64), dim3(256), 0, stream,
                       fflag, x, bdec, wt, wdecb, out, M);
}

// Round 13
// 1019.340 us; speedup vs baseline: 2.2070x; 2.2070x over previous
//
#include <hip/hip_runtime.h>
#include <hip/hip_bf16.h>
#include <stdint.h>

#define D_VIT 768
#define D_SAE 12288
#define TOPK 32
#define NC 32           // fast-path quorum: >=32 codes >= CQ(3.25)
#define CMAX 384        // candidate slots per row
#define THETA 3.1f      // encoder emission threshold (mfma-f32 domain)
#define NCF 48          // fallback superset size
#define CFB 512

typedef __attribute__((ext_vector_type(8))) short bf8_t;   // 8 bf16 (4 VGPRs)
typedef __attribute__((ext_vector_type(4))) float f4_t;    // 4 f32 acc
typedef __attribute__((ext_vector_type(4))) float f4v;
typedef const __attribute__((address_space(1))) void* gas_t;
typedef __attribute__((address_space(3))) void* las_t;

// ---------------- transpose W_enc (768 x 12288) -> wt f32 + wtb bf16 ---------
__global__ void k_transpose(const float* __restrict__ src, float* __restrict__ dst,
                            __hip_bfloat16* __restrict__ dstb) {
    __shared__ float t[32][33];
    int f0 = blockIdx.x * 32, k0 = blockIdx.y * 32;
    int tx = threadIdx.x, ty = threadIdx.y;
#pragma unroll
    for (int j = 0; j < 32; j += 8)
        t[ty + j][tx] = src[(size_t)(k0 + ty + j) * D_SAE + f0 + tx];
    __syncthreads();
#pragma unroll
    for (int j = 0; j < 32; j += 8) {
        float v = t[tx][ty + j];
        dst[(size_t)(f0 + ty + j) * D_VIT + k0 + tx] = v;
        dstb[(size_t)(f0 + ty + j) * D_VIT + k0 + tx] = __float2bfloat16(v);
    }
}

// ---------------- xb = bf16(x - b_dec) ---------------------------------------
__global__ __launch_bounds__(256) void k_cvt_x(const float* __restrict__ x,
    const float* __restrict__ bdec, __hip_bfloat16* __restrict__ xb, long long n) {
    long long i = ((long long)blockIdx.x * 256 + threadIdx.x) * 8;
    if (i >= n) return;
    float4 a = *reinterpret_cast<const float4*>(x + i);
    float4 b = *reinterpret_cast<const float4*>(x + i + 4);
    int kk = (int)(i % D_VIT);
    float4 c = *reinterpret_cast<const float4*>(bdec + kk);
    float4 d = *reinterpret_cast<const float4*>(bdec + kk + 4);
    union { __hip_bfloat16 h[8]; uint4 v; } o;
    o.h[0] = __float2bfloat16(a.x - c.x); o.h[1] = __float2bfloat16(a.y - c.y);
    o.h[2] = __float2bfloat16(a.z - c.z); o.h[3] = __float2bfloat16(a.w - c.w);
    o.h[4] = __float2bfloat16(b.x - d.x); o.h[5] = __float2bfloat16(b.y - d.y);
    o.h[6] = __float2bfloat16(b.z - d.z); o.h[7] = __float2bfloat16(b.w - d.w);
    *reinterpret_cast<uint4*>(xb + i) = o.v;
}

// ---------------- wdecb = bf16(wdec) -----------------------------------------
__global__ __launch_bounds__(256) void k_cvt_w(const float* __restrict__ wdec,
    __hip_bfloat16* __restrict__ wdecb, long long n) {
    long long i = ((long long)blockIdx.x * 256 + threadIdx.x) * 8;
    if (i >= n) return;
    float4 a = *reinterpret_cast<const float4*>(wdec + i);
    float4 b = *reinterpret_cast<const float4*>(wdec + i + 4);
    union { __hip_bfloat16 h[8]; uint4 v; } o;
    o.h[0] = __float2bfloat16(a.x); o.h[1] = __float2bfloat16(a.y);
    o.h[2] = __float2bfloat16(a.z); o.h[3] = __float2bfloat16(a.w);
    o.h[4] = __float2bfloat16(b.x); o.h[5] = __float2bfloat16(b.y);
    o.h[6] = __float2bfloat16(b.z); o.h[7] = __float2bfloat16(b.w);
    *reinterpret_cast<uint4*>(wdecb + i) = o.v;
}

// ---------------- zero per-row counters / flags -------------------------------
__global__ __launch_bounds__(256) void k_zero(int* __restrict__ cnt,
                                              int* __restrict__ fflag, int M) {
    int i = blockIdx.x * 256 + threadIdx.x;
    if (i < M) { cnt[i] = 0; fflag[i] = 0; }
}

// ------- 256x256x64 8-wave dbuf MFMA encoder -> candidate emission only ------
#define GBM 256
#define GBN 256
#define GBK 64
#define NKT (D_VIT / GBK)   // 12

__global__ __launch_bounds__(512, 2) void k_enc8(
    const __hip_bfloat16* __restrict__ xb, const __hip_bfloat16* __restrict__ wtb,
    int* __restrict__ cnt, int* __restrict__ candb, int mrows) {
    __shared__ __hip_bfloat16 lds[2][2][GBM * GBK];   // 128 KiB
    int tid = threadIdx.x;
    int lane = tid & 63, w = tid >> 6;
    int wm = w >> 2, wn = w & 3;
    int tile_m = blockIdx.y * GBM, tile_n = blockIdx.x * GBN;
    int lrow = lane & 15, lk = lane >> 4;
    int G0 = w * 64 + lane;

    f4_t acc[2][4][2][2] = {};

    auto STAGE = [&](int kt, int h, int b) {
#pragma unroll
        for (int j = 0; j < 2; ++j) {
            int G = G0 + j * 512;
            int r = G >> 3, s = G & 7;
            int gg = s ^ (r & 7);
            int half = h >> 1;
            if ((h & 1) == 0) {
                int ar = tile_m + half * 128 + r;
                if (ar >= mrows) ar = mrows - 1;
                const __hip_bfloat16* src = xb + (size_t)ar * D_VIT + kt * GBK + gg * 8;
                __builtin_amdgcn_global_load_lds((gas_t)src,
                    (las_t)(&lds[b][0][half * 8192 + (w * 64 + j * 512) * 8]), 16, 0, 0);
            } else {
                int br = tile_n + half * 128 + r;
                const __hip_bfloat16* src = wtb + (size_t)br * D_VIT + kt * GBK + gg * 8;
                __builtin_amdgcn_global_load_lds((gas_t)src,
                    (las_t)(&lds[b][1][half * 8192 + (w * 64 + j * 512) * 8]), 16, 0, 0);
            }
        }
    };

#define PHASE(MQ, NQ, BUF) do {                                                \
        const __hip_bfloat16* Ab = &lds[BUF][0][0];                            \
        const __hip_bfloat16* Bb = &lds[BUF][1][0];                            \
        bf8_t af[4][2], bv[2][2];                                              \
        _Pragma("unroll")                                                      \
        for (int f = 0; f < 4; ++f) {                                          \
            int ra = wm * 128 + (MQ) * 64 + f * 16 + lrow;                     \
            _Pragma("unroll")                                                  \
            for (int h = 0; h < 2; ++h) {                                      \
                int sl = (lk + 4 * h) ^ (ra & 7);                              \
                af[f][h] = *reinterpret_cast<const bf8_t*>(Ab + ra * GBK + sl * 8); \
            }                                                                  \
        }                                                                      \
        _Pragma("unroll")                                                      \
        for (int g = 0; g < 2; ++g) {                                          \
            int rb = wn * 64 + (NQ) * 32 + g * 16 + lrow;                      \
            _Pragma("unroll")                                                  \
            for (int h = 0; h < 2; ++h) {                                      \
                int sl = (lk + 4 * h) ^ (rb & 7);                              \
                bv[g][h] = *reinterpret_cast<const bf8_t*>(Bb + rb * GBK + sl * 8); \
            }                                                                  \
        }                                                                      \
        __builtin_amdgcn_s_setprio(1);                                         \
        _Pragma("unroll")                                                      \
        for (int h = 0; h < 2; ++h)                                            \
            _Pragma("unroll")                                                  \
            for (int f = 0; f < 4; ++f)                                        \
                _Pragma("unroll")                                              \
                for (int g = 0; g < 2; ++g)                                    \
                    acc[MQ][f][NQ][g] = __builtin_amdgcn_mfma_f32_16x16x32_bf16( \
                        bv[g][h], af[f][h], acc[MQ][f][NQ][g], 0, 0, 0);       \
        __builtin_amdgcn_s_setprio(0);                                         \
    } while (0)

#pragma unroll
    for (int h = 0; h < 4; ++h) STAGE(0, h, 0);

    int cur = 0;
#pragma unroll 1
    for (int t = 0; t < NKT; ++t) {
        int nb = cur ^ 1;
        bool pf = (t + 1 < NKT);
        if (pf) STAGE(t + 1, 0, nb);
        if (pf) asm volatile("s_waitcnt vmcnt(2)" ::: "memory");
        else    asm volatile("s_waitcnt vmcnt(0)" ::: "memory");
        __builtin_amdgcn_s_barrier();
        asm volatile("" ::: "memory");
        __builtin_amdgcn_sched_barrier(0);
        PHASE(0, 0, cur);
        if (pf) STAGE(t + 1, 1, nb);
        PHASE(1, 0, cur);
        if (pf) STAGE(t + 1, 2, nb);
        PHASE(0, 1, cur);
        if (pf) STAGE(t + 1, 3, nb);
        PHASE(1, 1, cur);
        asm volatile("" ::: "memory");
        __builtin_amdgcn_s_barrier();
        asm volatile("" ::: "memory");
        cur = nb;
    }
#undef PHASE

    // candidate emission: values >= THETA only; no acts store.
#pragma unroll
    for (int mq = 0; mq < 2; ++mq)
#pragma unroll
        for (int f = 0; f < 4; ++f) {
            int xr = tile_m + wm * 128 + mq * 64 + f * 16 + lrow;
            if (xr < mrows) {
#pragma unroll
                for (int nq = 0; nq < 2; ++nq)
#pragma unroll
                    for (int g = 0; g < 2; ++g) {
                        int fb = tile_n + wn * 64 + nq * 32 + g * 16 + lk * 4;
#pragma unroll
                        for (int q = 0; q < 4; ++q) {
                            float r = acc[mq][f][nq][g][q];
                            if (r >= THETA) {
                                int slot = atomicAdd(&cnt[xr], 1);
                                if (slot < CMAX) {
                                    union { __hip_bfloat16 h; unsigned short u; } cc;
                                    cc.h = __float2bfloat16(r);
                                    candb[(size_t)xr * CMAX + slot] =
                                        (int)(((unsigned)cc.u << 16) | (unsigned)(fb + q));
                                }
                            }
                        }
                    }
            }
        }
}

// -------- per-row select: candidate list -> band f64 rerank -> decode --------
__global__ __launch_bounds__(256) void k_select(
    const int* __restrict__ cnt, const int* __restrict__ candb,
    const float* __restrict__ x, const float* __restrict__ bdec,
    const float* __restrict__ wt, const __hip_bfloat16* __restrict__ wdecb,
    float* __restrict__ out, int* __restrict__ fflag) {
    int row = blockIdx.x, tid = threadIdx.x;

    __shared__ float xs[D_VIT];
    __shared__ int cand[CMAX];
    __shared__ float cvfin[CMAX];
    __shared__ float cexact[CMAX];
    __shared__ unsigned char cflag[CMAX];
    __shared__ short alist[CMAX];
    __shared__ float sval[TOPK];
    __shared__ int sidx[TOPK];
    __shared__ int s_nq, s_na, s_nd;
    __shared__ float s_vb;

    for (int c = tid; c < CMAX; c += 256) cflag[c] = 0;
    if (tid < TOPK) { sval[tid] = 0.f; sidx[tid] = 0; }
    if (tid == 0) { s_nq = 0; s_na = 0; s_nd = 0; s_vb = 0.f; }
    if (tid < 192) {
        const float* xp = x + (size_t)row * D_VIT + tid * 4;
        float4 xv = *reinterpret_cast<const float4*>(xp);
        float4 bv = *reinterpret_cast<const float4*>(bdec + tid * 4);
        xs[tid * 4 + 0] = xv.x - bv.x; xs[tid * 4 + 1] = xv.y - bv.y;
        xs[tid * 4 + 2] = xv.z - bv.z; xs[tid * 4 + 3] = xv.w - bv.w;
    }
    int C0 = cnt[row];
    int C = C0 < CMAX ? C0 : CMAX;
    for (int c = tid; c < C; c += 256) cand[c] = candb[(size_t)row * CMAX + c];
    __syncthreads();

    // quorum: >=NC codes >= bf16(3.25). Exclusion proof: 32nd exact >=
    // 3.25-0.016-0.019 = 3.215 > excluded exact < 3.1+0.035 = 3.135.
    unsigned CQ;
    { union { __hip_bfloat16 h; unsigned short u; } t2; t2.h = __float2bfloat16(3.25f); CQ = t2.u; }
    int nql = 0;
    for (int c = tid; c < C; c += 256)
        if (((unsigned)cand[c] >> 16) >= CQ) nql++;
    if (nql) atomicAdd(&s_nq, nql);
    __syncthreads();
    if (C0 > CMAX || s_nq < NC) {
        if (tid == 0) fflag[row] = 1;
        return;
    }

    // vb = 32nd-largest code (index tiebreak)
    for (int c = tid; c < C; c += 256) {
        unsigned pk = (unsigned)cand[c];
        unsigned mc = pk >> 16; int mi = (int)(pk & 0xffffu);
        int rk = 0;
        for (int j = 0; j < C; ++j) {
            unsigned pj = (unsigned)cand[j];
            unsigned cj = pj >> 16; int ij = (int)(pj & 0xffffu);
            rk += (cj > mc) || (cj == mc && ij < mi);
        }
        if (rk == 31) s_vb = __uint_as_float(mc << 16);
    }
    __syncthreads();

    // partition: definite-in / ambiguous band / excluded
    {
        float vb = s_vb, band = 0.025f + 0.018f * vb;
        for (int c = tid; c < C; c += 256) {
            float v = __uint_as_float(((unsigned)cand[c] >> 16) << 16);
            if (v > vb + band) { cflag[c] = 2; cvfin[c] = v; atomicAdd(&s_nd, 1); }
            else if (v >= vb - band) { int a = atomicAdd(&s_na, 1); alist[a] = (short)c; cflag[c] = 1; }
        }
    }
    __syncthreads();
    int na = s_na, nd = s_nd;

    // f64 rerank of band only: 8 cands x 32 threads
    for (int base = 0; base < na; base += 8) {
        int ai = base + (tid >> 5), sub = tid & 31;
        if (ai < na) {
            int c = alist[ai];
            int f = (int)(((unsigned)cand[c]) & 0xffffu);
            const float* wr = wt + (size_t)f * D_VIT;
            double acc = 0.0;
            for (int k = sub * 4; k < D_VIT; k += 128) {
                float4 wv = *reinterpret_cast<const float4*>(wr + k);
                float4 xv = *reinterpret_cast<const float4*>(xs + k);
                acc += (double)wv.x * xv.x + (double)wv.y * xv.y
                     + (double)wv.z * xv.z + (double)wv.w * xv.w;
            }
            acc += __shfl_xor(acc, 1);  acc += __shfl_xor(acc, 2);
            acc += __shfl_xor(acc, 4);  acc += __shfl_xor(acc, 8);
            acc += __shfl_xor(acc, 16);
            if (sub == 0) cexact[c] = (float)(acc > 0.0 ? acc : 0.0);
        }
    }
    __syncthreads();

    // choose top (32-nd) of the band by exact value
    {
        int kq = TOPK - nd;
        for (int c = tid; c < C; c += 256) if (cflag[c] == 1) {
            float ex = cexact[c]; int mi = (int)(((unsigned)cand[c]) & 0xffffu);
            int rA = 0;
            for (int j = 0; j < na; ++j) {
                int cj = alist[j];
                float ej = cexact[cj]; int ij = (int)(((unsigned)cand[cj]) & 0xffffu);
                rA += (ej > ex) || (ej == ex && ij < mi);
            }
            if (rA < kq) { cflag[c] = 3; cvfin[c] = ex; }
        }
    }
    __syncthreads();

    // deterministic slot routing among the chosen (content-based)
    for (int c = tid; c < C; c += 256) if (cflag[c] >= 2) {
        float mv = cvfin[c]; int mi = (int)(((unsigned)cand[c]) & 0xffffu);
        int rk = 0;
        for (int j = 0; j < C; ++j) if (cflag[j] >= 2) {
            float vj = cvfin[j]; int ij = (int)(((unsigned)cand[j]) & 0xffffu);
            rk += (vj > mv) || (vj == mv && ij < mi);
        }
        if (rk < TOPK) { sval[rk] = mv; sidx[rk] = mi; }
    }
    __syncthreads();

    // decode: 192 threads x 4 coords, uint2 bf16x4 loads, nt store
    if (tid < 192) {
        int d0 = tid * 4;
        float4 o = *reinterpret_cast<const float4*>(bdec + d0);
#pragma unroll
        for (int j = 0; j < TOPK; ++j) {
            float s = sval[j];
            uint2 u = *reinterpret_cast<const uint2*>(wdecb + (size_t)sidx[j] * D_VIT + d0);
            o.x = fmaf(s, __uint_as_float(u.x << 16), o.x);
            o.y = fmaf(s, __uint_as_float(u.x & 0xffff0000u), o.y);
            o.z = fmaf(s, __uint_as_float(u.y << 16), o.z);
            o.w = fmaf(s, __uint_as_float(u.y & 0xffff0000u), o.w);
        }
        f4v ov; ov.x = o.x; ov.y = o.y; ov.z = o.z; ov.w = o.w;
        __builtin_nontemporal_store(ov,
            reinterpret_cast<f4v*>(out + (size_t)row * D_VIT + d0));
    }
}

// -------- fallback: coalesced full f32 recompute, any-distribution exact -----
__global__ __launch_bounds__(256) void k_fallback(
    const int* __restrict__ fflag, const float* __restrict__ x,
    const float* __restrict__ bdec, const float* __restrict__ wt,
    const __hip_bfloat16* __restrict__ wdecb, float* __restrict__ out) {
    int row = blockIdx.x;
    if (fflag[row] == 0) return;
    int tid = threadIdx.x;

    __shared__ float xs[D_VIT];
    __shared__ unsigned short actl[D_SAE];   // bf16 codes of f32 acts
    __shared__ unsigned int hist1[256];
    __shared__ unsigned int hist2[128];
    __shared__ int cand[CFB];
    __shared__ double cval[CFB];
    __shared__ float sval[TOPK];
    __shared__ int sidx[TOPK];
    __shared__ int s_cnt, s_b1, s_code;
    __shared__ unsigned int s_above;

    hist1[tid] = 0;
    if (tid < 128) hist2[tid] = 0;
    if (tid < TOPK) { sval[tid] = 0.f; sidx[tid] = 0; }
    if (tid == 0) { s_cnt = 0; s_b1 = -1; s_code = 1; s_above = 0; }
    if (tid < 192) {
        float4 xv = *reinterpret_cast<const float4*>(x + (size_t)row * D_VIT + tid * 4);
        float4 bv = *reinterpret_cast<const float4*>(bdec + tid * 4);
        xs[tid * 4 + 0] = xv.x - bv.x; xs[tid * 4 + 1] = xv.y - bv.y;
        xs[tid * 4 + 2] = xv.z - bv.z; xs[tid * 4 + 3] = xv.w - bv.w;
    }
    __syncthreads();

    // coalesced exact-f32 recompute: 4 threads/feature, 64 features/pass
    int fg = tid >> 2, sub = tid & 3;
    for (int pass = 0; pass < D_SAE / 64; ++pass) {
        int f = pass * 64 + fg;
        const float* wr = wt + (size_t)f * D_VIT;
        float a = 0.f;
        for (int j = 0; j < 48; ++j) {
            int k = sub * 4 + j * 16;
            float4 wv = *reinterpret_cast<const float4*>(wr + k);
            float4 xv = *reinterpret_cast<const float4*>(xs + k);
            a = fmaf(wv.x, xv.x, a); a = fmaf(wv.y, xv.y, a);
            a = fmaf(wv.z, xv.z, a); a = fmaf(wv.w, xv.w, a);
        }
        a += __shfl_xor(a, 1); a += __shfl_xor(a, 2);
        if (sub == 0) {
            union { __hip_bfloat16 h; unsigned short u; } cc;
            cc.h = __float2bfloat16(fmaxf(a, 0.f));
            actl[f] = cc.u;
        }
    }
    __syncthreads();

    // two-level histogram threshold for top-NCF superset (codes from LDS)
    for (int i = tid; i < D_SAE; i += 256) {
        unsigned c = actl[i];
        if (c && c < 0x8000u) atomicAdd(&hist1[c >> 7], 1u);
    }
    __syncthreads();
    if (tid < 64) {
        int l = tid;
        unsigned c0 = hist1[4 * l], c1 = hist1[4 * l + 1],
                 c2 = hist1[4 * l + 2], c3 = hist1[4 * l + 3];
        unsigned S = c0 + c1 + c2 + c3;
#pragma unroll
        for (int o = 1; o < 64; o <<= 1) {
            unsigned t = __shfl_down(S, o);
            if (l + o < 64) S += t;
        }
        unsigned above = __shfl_down(S, 1);
        if (l == 63) above = 0;
        if (S >= NCF && above < NCF) {
            int b1; unsigned ab;
            if (above + c3 >= NCF)                { b1 = 4 * l + 3; ab = above; }
            else if (above + c3 + c2 >= NCF)      { b1 = 4 * l + 2; ab = above + c3; }
            else if (above + c3 + c2 + c1 >= NCF) { b1 = 4 * l + 1; ab = above + c3 + c2; }
            else                                  { b1 = 4 * l;     ab = above + c3 + c2 + c1; }
            s_b1 = b1; s_above = ab;
        }
    }
    __syncthreads();
    int b1 = s_b1;
    if (b1 >= 0) {
        for (int i = tid; i < D_SAE; i += 256) {
            unsigned c = actl[i];
            if (c && c < 0x8000u && (int)(c >> 7) == b1) atomicAdd(&hist2[c & 127u], 1u);
        }
        __syncthreads();
        if (tid < 64) {
            int l = tid;
            unsigned above0 = s_above;
            unsigned c0 = hist2[2 * l], c1 = hist2[2 * l + 1];
            unsigned S = c0 + c1;
#pragma unroll
            for (int o = 1; o < 64; o <<= 1) {
                unsigned t = __shfl_down(S, o);
                if (l + o < 64) S += t;
            }
            unsigned ab2 = __shfl_down(S, 1);
            if (l == 63) ab2 = 0;
            if (above0 + S >= NCF && above0 + ab2 < NCF) {
                if (above0 + ab2 + c1 >= NCF) s_code = (b1 << 7) | (2 * l + 1);
                else                          s_code = (b1 << 7) | (2 * l);
            }
        }
        __syncthreads();
    }
    int code = s_code;

    for (int i = tid; i < D_SAE; i += 256) {
        unsigned c = actl[i];
        if (c < 0x8000u && (int)c >= code) {
            int slot = atomicAdd(&s_cnt, 1);
            if (slot < CFB) cand[slot] = i;
        }
    }
    __syncthreads();
    int C = s_cnt < CFB ? s_cnt : CFB;

    // f64 rerank all candidates
    for (int base = 0; base < C; base += 64) {
        int ai = base + (tid >> 2), sb = tid & 3;
        if (ai < C) {
            const float* wr = wt + (size_t)cand[ai] * D_VIT;
            double a = 0.0;
            for (int k = sb * 4; k < D_VIT; k += 16) {
                float4 wv = *reinterpret_cast<const float4*>(wr + k);
                float4 xv = *reinterpret_cast<const float4*>(xs + k);
                a += (double)wv.x * xv.x + (double)wv.y * xv.y
                   + (double)wv.z * xv.z + (double)wv.w * xv.w;
            }
            a += __shfl_xor(a, 1); a += __shfl_xor(a, 2);
            if (sb == 0) cval[ai] = a > 0.0 ? a : 0.0;
        }
    }
    __syncthreads();

    // exact top-32 routing (content-based)
    for (int c = tid; c < C; c += 256) {
        double mv = cval[c]; int mi = cand[c]; int rk = 0;
        for (int j = 0; j < C; ++j) {
            double vj = cval[j]; int ij = cand[j];
            rk += (vj > mv) || (vj == mv && ij < mi);
        }
        if (rk < TOPK) { sval[rk] = (float)mv; sidx[rk] = mi; }
    }
    __syncthreads();

    if (tid < 192) {
        int d0 = tid * 4;
        float4 o = *reinterpret_cast<const float4*>(bdec + d0);
#pragma unroll
        for (int j = 0; j < TOPK; ++j) {
            float s = sval[j];
            uint2 u = *reinterpret_cast<const uint2*>(wdecb + (size_t)sidx[j] * D_VIT + d0);
            o.x = fmaf(s, __uint_as_float(u.x << 16), o.x);
            o.y = fmaf(s, __uint_as_float(u.x & 0xffff0000u), o.y);
            o.z = fmaf(s, __uint_as_float(u.y << 16), o.z);
            o.w = fmaf(s, __uint_as_float(u.y & 0xffff0000u), o.w);
        }
        *reinterpret_cast<float4*>(out + (size_t)row * D_VIT + d0) = o;
    }
}

extern "C" void kernel_launch(void* const* d_in, const int* in_sizes, int n_in,
                              void* d_out, int out_size, void* d_ws, size_t ws_size,
                              hipStream_t stream) {
    const float* x    = (const float*)d_in[0];
    const float* wenc = (const float*)d_in[1];
    const float* wdec = (const float*)d_in[2];
    const float* bdec = (const float*)d_in[3];
    float* out = (float*)d_out;
    int M = in_sizes[0] / D_VIT;

    size_t wt_b    = (size_t)D_SAE * D_VIT * sizeof(float);
    size_t wtb_b   = (size_t)D_SAE * D_VIT * sizeof(__hip_bfloat16);
    size_t xb_b    = (size_t)M * D_VIT * sizeof(__hip_bfloat16);
    size_t wdecb_b = (size_t)D_SAE * D_VIT * sizeof(__hip_bfloat16);
    size_t cnt_b   = (size_t)M * sizeof(int);
    size_t flag_b  = (size_t)M * sizeof(int);

    char* p = (char*)d_ws;
    float* wt             = (float*)p;              p += wt_b;
    __hip_bfloat16* wtb   = (__hip_bfloat16*)p;     p += wtb_b;
    __hip_bfloat16* xb    = (__hip_bfloat16*)p;     p += xb_b;
    __hip_bfloat16* wdecb = (__hip_bfloat16*)p;     p += wdecb_b;
    int* cnt              = (int*)p;                p += cnt_b;
    int* fflag            = (int*)p;                p += flag_b;
    int* candb            = (int*)p;

    {
        int blocks = (M + 255) / 256;
        hipLaunchKernelGGL(k_zero, dim3(blocks), dim3(256), 0, stream, cnt, fflag, M);
    }
    {
        dim3 g(D_SAE / 32, D_VIT / 32), b(32, 8);
        hipLaunchKernelGGL(k_transpose, g, b, 0, stream, wenc, wt, wtb);
    }
    {
        long long n = (long long)M * D_VIT;
        int blocks = (int)((n / 8 + 255) / 256);
        hipLaunchKernelGGL(k_cvt_x, dim3(blocks), dim3(256), 0, stream, x, bdec, xb, n);
    }
    {
        long long n = (long long)D_SAE * D_VIT;
        int blocks = (int)((n / 8 + 255) / 256);
        hipLaunchKernelGGL(k_cvt_w, dim3(blocks), dim3(256), 0, stream, wdec, wdecb, n);
    }
    {
        dim3 ge(D_SAE / GBN, (M + GBM - 1) / GBM), be(512);
        hipLaunchKernelGGL(k_enc8, ge, be, 0, stream, xb, wtb, cnt, candb, M);
    }
    hipLaunchKernelGGL(k_select, dim3(M), dim3(256), 0, stream,
                       cnt, candb, x, bdec, wt, wdecb, out, fflag);
    hipLaunchKernelGGL(k_fallback, dim3(M), dim3(256), 0, stream,
                       fflag, x, bdec, wt, wdecb, out);
}

// Round 14
// 693.758 us; speedup vs baseline: 3.2427x; 1.4693x over previous
//
#include <hip/hip_runtime.h>
#include <hip/hip_bf16.h>
#include <stdint.h>

#define D_VIT 768
#define D_SAE 12288
#define TOPK 32
#define NC 32           // fast-path quorum: >=32 codes >= CQ(3.25)
#define CMAX 384        // candidate slots per row
#define THETA 3.1f      // encoder emission threshold (mfma-f32 domain)
#define SLOTS 24        // LDS staging slots per (row, block-col); overflow->fallback
#define NCF 48          // fallback superset size
#define CFB 512

typedef __attribute__((ext_vector_type(8))) short bf8_t;   // 8 bf16 (4 VGPRs)
typedef __attribute__((ext_vector_type(4))) float f4_t;    // 4 f32 acc
typedef __attribute__((ext_vector_type(4))) float f4v;
typedef const __attribute__((address_space(1))) void* gas_t;
typedef __attribute__((address_space(3))) void* las_t;

// ---------------- transpose W_enc (768 x 12288) -> wt f32 + wtb bf16 ---------
__global__ void k_transpose(const float* __restrict__ src, float* __restrict__ dst,
                            __hip_bfloat16* __restrict__ dstb) {
    __shared__ float t[32][33];
    int f0 = blockIdx.x * 32, k0 = blockIdx.y * 32;
    int tx = threadIdx.x, ty = threadIdx.y;
#pragma unroll
    for (int j = 0; j < 32; j += 8)
        t[ty + j][tx] = src[(size_t)(k0 + ty + j) * D_SAE + f0 + tx];
    __syncthreads();
#pragma unroll
    for (int j = 0; j < 32; j += 8) {
        float v = t[tx][ty + j];
        dst[(size_t)(f0 + ty + j) * D_VIT + k0 + tx] = v;
        dstb[(size_t)(f0 + ty + j) * D_VIT + k0 + tx] = __float2bfloat16(v);
    }
}

// ---------------- xb = bf16(x - b_dec) ---------------------------------------
__global__ __launch_bounds__(256) void k_cvt_x(const float* __restrict__ x,
    const float* __restrict__ bdec, __hip_bfloat16* __restrict__ xb, long long n) {
    long long i = ((long long)blockIdx.x * 256 + threadIdx.x) * 8;
    if (i >= n) return;
    float4 a = *reinterpret_cast<const float4*>(x + i);
    float4 b = *reinterpret_cast<const float4*>(x + i + 4);
    int kk = (int)(i % D_VIT);
    float4 c = *reinterpret_cast<const float4*>(bdec + kk);
    float4 d = *reinterpret_cast<const float4*>(bdec + kk + 4);
    union { __hip_bfloat16 h[8]; uint4 v; } o;
    o.h[0] = __float2bfloat16(a.x - c.x); o.h[1] = __float2bfloat16(a.y - c.y);
    o.h[2] = __float2bfloat16(a.z - c.z); o.h[3] = __float2bfloat16(a.w - c.w);
    o.h[4] = __float2bfloat16(b.x - d.x); o.h[5] = __float2bfloat16(b.y - d.y);
    o.h[6] = __float2bfloat16(b.z - d.z); o.h[7] = __float2bfloat16(b.w - d.w);
    *reinterpret_cast<uint4*>(xb + i) = o.v;
}

// ---------------- wdecb = bf16(wdec) -----------------------------------------
__global__ __launch_bounds__(256) void k_cvt_w(const float* __restrict__ wdec,
    __hip_bfloat16* __restrict__ wdecb, long long n) {
    long long i = ((long long)blockIdx.x * 256 + threadIdx.x) * 8;
    if (i >= n) return;
    float4 a = *reinterpret_cast<const float4*>(wdec + i);
    float4 b = *reinterpret_cast<const float4*>(wdec + i + 4);
    union { __hip_bfloat16 h[8]; uint4 v; } o;
    o.h[0] = __float2bfloat16(a.x); o.h[1] = __float2bfloat16(a.y);
    o.h[2] = __float2bfloat16(a.z); o.h[3] = __float2bfloat16(a.w);
    o.h[4] = __float2bfloat16(b.x); o.h[5] = __float2bfloat16(b.y);
    o.h[6] = __float2bfloat16(b.z); o.h[7] = __float2bfloat16(b.w);
    *reinterpret_cast<uint4*>(wdecb + i) = o.v;
}

// ---------------- zero per-row counters / flags -------------------------------
__global__ __launch_bounds__(256) void k_zero(int* __restrict__ cnt,
                                              int* __restrict__ fflag, int M) {
    int i = blockIdx.x * 256 + threadIdx.x;
    if (i < M) { cnt[i] = 0; fflag[i] = 0; }
}

// ------- 256x256x64 8-wave dbuf MFMA encoder -> LDS-staged candidate emit ----
#define GBM 256
#define GBN 256
#define GBK 64
#define NKT (D_VIT / GBK)   // 12

__global__ __launch_bounds__(512, 2) void k_enc8(
    const __hip_bfloat16* __restrict__ xb, const __hip_bfloat16* __restrict__ wtb,
    int* __restrict__ cnt, int* __restrict__ candb, int mrows) {
    __shared__ __hip_bfloat16 lds[2][2][GBM * GBK];   // 128 KiB (reused by epilogue)
    int tid = threadIdx.x;
    int lane = tid & 63, w = tid >> 6;
    int wm = w >> 2, wn = w & 3;
    int tile_m = blockIdx.y * GBM, tile_n = blockIdx.x * GBN;
    int lrow = lane & 15, lk = lane >> 4;
    int G0 = w * 64 + lane;

    f4_t acc[2][4][2][2] = {};

    auto STAGE = [&](int kt, int h, int b) {
#pragma unroll
        for (int j = 0; j < 2; ++j) {
            int G = G0 + j * 512;
            int r = G >> 3, s = G & 7;
            int gg = s ^ (r & 7);
            int half = h >> 1;
            if ((h & 1) == 0) {
                int ar = tile_m + half * 128 + r;
                if (ar >= mrows) ar = mrows - 1;
                const __hip_bfloat16* src = xb + (size_t)ar * D_VIT + kt * GBK + gg * 8;
                __builtin_amdgcn_global_load_lds((gas_t)src,
                    (las_t)(&lds[b][0][half * 8192 + (w * 64 + j * 512) * 8]), 16, 0, 0);
            } else {
                int br = tile_n + half * 128 + r;
                const __hip_bfloat16* src = wtb + (size_t)br * D_VIT + kt * GBK + gg * 8;
                __builtin_amdgcn_global_load_lds((gas_t)src,
                    (las_t)(&lds[b][1][half * 8192 + (w * 64 + j * 512) * 8]), 16, 0, 0);
            }
        }
    };

#define PHASE(MQ, NQ, BUF) do {                                                \
        const __hip_bfloat16* Ab = &lds[BUF][0][0];                            \
        const __hip_bfloat16* Bb = &lds[BUF][1][0];                            \
        bf8_t af[4][2], bv[2][2];                                              \
        _Pragma("unroll")                                                      \
        for (int f = 0; f < 4; ++f) {                                          \
            int ra = wm * 128 + (MQ) * 64 + f * 16 + lrow;                     \
            _Pragma("unroll")                                                  \
            for (int h = 0; h < 2; ++h) {                                      \
                int sl = (lk + 4 * h) ^ (ra & 7);                              \
                af[f][h] = *reinterpret_cast<const bf8_t*>(Ab + ra * GBK + sl * 8); \
            }                                                                  \
        }                                                                      \
        _Pragma("unroll")                                                      \
        for (int g = 0; g < 2; ++g) {                                          \
            int rb = wn * 64 + (NQ) * 32 + g * 16 + lrow;                      \
            _Pragma("unroll")                                                  \
            for (int h = 0; h < 2; ++h) {                                      \
                int sl = (lk + 4 * h) ^ (rb & 7);                              \
                bv[g][h] = *reinterpret_cast<const bf8_t*>(Bb + rb * GBK + sl * 8); \
            }                                                                  \
        }                                                                      \
        __builtin_amdgcn_s_setprio(1);                                         \
        _Pragma("unroll")                                                      \
        for (int h = 0; h < 2; ++h)                                            \
            _Pragma("unroll")                                                  \
            for (int f = 0; f < 4; ++f)                                        \
                _Pragma("unroll")                                              \
                for (int g = 0; g < 2; ++g)                                    \
                    acc[MQ][f][NQ][g] = __builtin_amdgcn_mfma_f32_16x16x32_bf16( \
                        bv[g][h], af[f][h], acc[MQ][f][NQ][g], 0, 0, 0);       \
        __builtin_amdgcn_s_setprio(0);                                         \
    } while (0)

#pragma unroll
    for (int h = 0; h < 4; ++h) STAGE(0, h, 0);

    int cur = 0;
#pragma unroll 1
    for (int t = 0; t < NKT; ++t) {
        int nb = cur ^ 1;
        bool pf = (t + 1 < NKT);
        if (pf) STAGE(t + 1, 0, nb);
        if (pf) asm volatile("s_waitcnt vmcnt(2)" ::: "memory");
        else    asm volatile("s_waitcnt vmcnt(0)" ::: "memory");
        __builtin_amdgcn_s_barrier();
        asm volatile("" ::: "memory");
        __builtin_amdgcn_sched_barrier(0);
        PHASE(0, 0, cur);
        if (pf) STAGE(t + 1, 1, nb);
        PHASE(1, 0, cur);
        if (pf) STAGE(t + 1, 2, nb);
        PHASE(0, 1, cur);
        if (pf) STAGE(t + 1, 3, nb);
        PHASE(1, 1, cur);
        asm volatile("" ::: "memory");
        __builtin_amdgcn_s_barrier();
        asm volatile("" ::: "memory");
        cur = nb;
    }
#undef PHASE

    // ---- epilogue: LDS-staged candidate emission (no global atomics in loop)
    __syncthreads();                      // all MFMA reads of lds done
    int* scnt  = reinterpret_cast<int*>(&lds[0][0][0]);   // [256]
    int* scand = scnt + 256;                              // [256][SLOTS]
    for (int r = tid; r < 256; r += 512) scnt[r] = 0;
    __syncthreads();

#pragma unroll
    for (int mq = 0; mq < 2; ++mq)
#pragma unroll
        for (int f = 0; f < 4; ++f) {
            int lr = wm * 128 + mq * 64 + f * 16 + lrow;
            int xr = tile_m + lr;
            if (xr < mrows) {
#pragma unroll
                for (int nq = 0; nq < 2; ++nq)
#pragma unroll
                    for (int g = 0; g < 2; ++g) {
                        int fb = tile_n + wn * 64 + nq * 32 + g * 16 + lk * 4;
#pragma unroll
                        for (int q = 0; q < 4; ++q) {
                            float r = acc[mq][f][nq][g][q];
                            if (r >= THETA) {
                                int slot = atomicAdd(&scnt[lr], 1);   // LDS atomic
                                if (slot < SLOTS) {
                                    union { __hip_bfloat16 h; unsigned short u; } cc;
                                    cc.h = __float2bfloat16(r);
                                    scand[lr * SLOTS + slot] =
                                        (int)(((unsigned)cc.u << 16) | (unsigned)(fb + q));
                                }
                            }
                        }
                    }
            }
        }
    __syncthreads();

    // flush: one global atomic per (row, block) — 256 in parallel
    if (tid < 256) {
        int xr = tile_m + tid;
        if (xr < mrows) {
            int c = scnt[tid];
            if (c > SLOTS) {
                atomicAdd(&cnt[xr], CMAX + 1);     // poison -> fallback (sum-deterministic)
            } else if (c > 0) {
                int base = atomicAdd(&cnt[xr], c);
                for (int i = 0; i < c; ++i) {
                    int g = base + i;
                    if (g < CMAX) candb[(size_t)xr * CMAX + g] = scand[tid * SLOTS + i];
                }
            }
        }
    }
}

// -------- per-row select: candidate list -> band f64 rerank -> decode --------
__global__ __launch_bounds__(256) void k_select(
    const int* __restrict__ cnt, const int* __restrict__ candb,
    const float* __restrict__ x, const float* __restrict__ bdec,
    const float* __restrict__ wt, const __hip_bfloat16* __restrict__ wdecb,
    float* __restrict__ out, int* __restrict__ fflag) {
    int row = blockIdx.x, tid = threadIdx.x;

    __shared__ float xs[D_VIT];
    __shared__ int cand[CMAX];
    __shared__ float cvfin[CMAX];
    __shared__ float cexact[CMAX];
    __shared__ unsigned char cflag[CMAX];
    __shared__ short alist[CMAX];
    __shared__ float sval[TOPK];
    __shared__ int sidx[TOPK];
    __shared__ int s_nq, s_na, s_nd;
    __shared__ float s_vb;

    for (int c = tid; c < CMAX; c += 256) cflag[c] = 0;
    if (tid < TOPK) { sval[tid] = 0.f; sidx[tid] = 0; }
    if (tid == 0) { s_nq = 0; s_na = 0; s_nd = 0; s_vb = 0.f; }
    if (tid < 192) {
        const float* xp = x + (size_t)row * D_VIT + tid * 4;
        float4 xv = *reinterpret_cast<const float4*>(xp);
        float4 bv = *reinterpret_cast<const float4*>(bdec + tid * 4);
        xs[tid * 4 + 0] = xv.x - bv.x; xs[tid * 4 + 1] = xv.y - bv.y;
        xs[tid * 4 + 2] = xv.z - bv.z; xs[tid * 4 + 3] = xv.w - bv.w;
    }
    int C0 = cnt[row];
    int C = C0 < CMAX ? C0 : CMAX;
    for (int c = tid; c < C; c += 256) cand[c] = candb[(size_t)row * CMAX + c];
    __syncthreads();

    // quorum: >=NC codes >= bf16(3.25). Exclusion proof: 32nd exact >=
    // 3.25-0.016-0.019 = 3.215 > excluded exact < 3.1+0.035 = 3.135.
    unsigned CQ;
    { union { __hip_bfloat16 h; unsigned short u; } t2; t2.h = __float2bfloat16(3.25f); CQ = t2.u; }
    int nql = 0;
    for (int c = tid; c < C; c += 256)
        if (((unsigned)cand[c] >> 16) >= CQ) nql++;
    if (nql) atomicAdd(&s_nq, nql);
    __syncthreads();
    if (C0 > CMAX || s_nq < NC) {
        if (tid == 0) fflag[row] = 1;
        return;
    }

    // vb = 32nd-largest code (index tiebreak)
    for (int c = tid; c < C; c += 256) {
        unsigned pk = (unsigned)cand[c];
        unsigned mc = pk >> 16; int mi = (int)(pk & 0xffffu);
        int rk = 0;
        for (int j = 0; j < C; ++j) {
            unsigned pj = (unsigned)cand[j];
            unsigned cj = pj >> 16; int ij = (int)(pj & 0xffffu);
            rk += (cj > mc) || (cj == mc && ij < mi);
        }
        if (rk == 31) s_vb = __uint_as_float(mc << 16);
    }
    __syncthreads();

    // partition: definite-in / ambiguous band / excluded
    {
        float vb = s_vb, band = 0.025f + 0.018f * vb;
        for (int c = tid; c < C; c += 256) {
            float v = __uint_as_float(((unsigned)cand[c] >> 16) << 16);
            if (v > vb + band) { cflag[c] = 2; cvfin[c] = v; atomicAdd(&s_nd, 1); }
            else if (v >= vb - band) { int a = atomicAdd(&s_na, 1); alist[a] = (short)c; cflag[c] = 1; }
        }
    }
    __syncthreads();
    int na = s_na, nd = s_nd;

    // f64 rerank of band only: 8 cands x 32 threads
    for (int base = 0; base < na; base += 8) {
        int ai = base + (tid >> 5), sub = tid & 31;
        if (ai < na) {
            int c = alist[ai];
            int f = (int)(((unsigned)cand[c]) & 0xffffu);
            const float* wr = wt + (size_t)f * D_VIT;
            double acc = 0.0;
            for (int k = sub * 4; k < D_VIT; k += 128) {
                float4 wv = *reinterpret_cast<const float4*>(wr + k);
                float4 xv = *reinterpret_cast<const float4*>(xs + k);
                acc += (double)wv.x * xv.x + (double)wv.y * xv.y
                     + (double)wv.z * xv.z + (double)wv.w * xv.w;
            }
            acc += __shfl_xor(acc, 1);  acc += __shfl_xor(acc, 2);
            acc += __shfl_xor(acc, 4);  acc += __shfl_xor(acc, 8);
            acc += __shfl_xor(acc, 16);
            if (sub == 0) cexact[c] = (float)(acc > 0.0 ? acc : 0.0);
        }
    }
    __syncthreads();

    // choose top (32-nd) of the band by exact value
    {
        int kq = TOPK - nd;
        for (int c = tid; c < C; c += 256) if (cflag[c] == 1) {
            float ex = cexact[c]; int mi = (int)(((unsigned)cand[c]) & 0xffffu);
            int rA = 0;
            for (int j = 0; j < na; ++j) {
                int cj = alist[j];
                float ej = cexact[cj]; int ij = (int)(((unsigned)cand[cj]) & 0xffffu);
                rA += (ej > ex) || (ej == ex && ij < mi);
            }
            if (rA < kq) { cflag[c] = 3; cvfin[c] = ex; }
        }
    }
    __syncthreads();

    // deterministic slot routing among the chosen (content-based)
    for (int c = tid; c < C; c += 256) if (cflag[c] >= 2) {
        float mv = cvfin[c]; int mi = (int)(((unsigned)cand[c]) & 0xffffu);
        int rk = 0;
        for (int j = 0; j < C; ++j) if (cflag[j] >= 2) {
            float vj = cvfin[j]; int ij = (int)(((unsigned)cand[j]) & 0xffffu);
            rk += (vj > mv) || (vj == mv && ij < mi);
        }
        if (rk < TOPK) { sval[rk] = mv; sidx[rk] = mi; }
    }
    __syncthreads();

    // decode: 192 threads x 4 coords, uint2 bf16x4 loads, nt store
    if (tid < 192) {
        int d0 = tid * 4;
        float4 o = *reinterpret_cast<const float4*>(bdec + d0);
#pragma unroll
        for (int j = 0; j < TOPK; ++j) {
            float s = sval[j];
            uint2 u = *reinterpret_cast<const uint2*>(wdecb + (size_t)sidx[j] * D_VIT + d0);
            o.x = fmaf(s, __uint_as_float(u.x << 16), o.x);
            o.y = fmaf(s, __uint_as_float(u.x & 0xffff0000u), o.y);
            o.z = fmaf(s, __uint_as_float(u.y << 16), o.z);
            o.w = fmaf(s, __uint_as_float(u.y & 0xffff0000u), o.w);
        }
        f4v ov; ov.x = o.x; ov.y = o.y; ov.z = o.z; ov.w = o.w;
        __builtin_nontemporal_store(ov,
            reinterpret_cast<f4v*>(out + (size_t)row * D_VIT + d0));
    }
}

// -------- fallback: coalesced full f32 recompute, any-distribution exact -----
__global__ __launch_bounds__(256) void k_fallback(
    const int* __restrict__ fflag, const float* __restrict__ x,
    const float* __restrict__ bdec, const float* __restrict__ wt,
    const __hip_bfloat16* __restrict__ wdecb, float* __restrict__ out) {
    int row = blockIdx.x;
    if (fflag[row] == 0) return;
    int tid = threadIdx.x;

    __shared__ float xs[D_VIT];
    __shared__ unsigned short actl[D_SAE];   // bf16 codes of f32 acts
    __shared__ unsigned int hist1[256];
    __shared__ unsigned int hist2[128];
    __shared__ int cand[CFB];
    __shared__ double cval[CFB];
    __shared__ float sval[TOPK];
    __shared__ int sidx[TOPK];
    __shared__ int s_cnt, s_b1, s_code;
    __shared__ unsigned int s_above;

    hist1[tid] = 0;
    if (tid < 128) hist2[tid] = 0;
    if (tid < TOPK) { sval[tid] = 0.f; sidx[tid] = 0; }
    if (tid == 0) { s_cnt = 0; s_b1 = -1; s_code = 1; s_above = 0; }
    if (tid < 192) {
        float4 xv = *reinterpret_cast<const float4*>(x + (size_t)row * D_VIT + tid * 4);
        float4 bv = *reinterpret_cast<const float4*>(bdec + tid * 4);
        xs[tid * 4 + 0] = xv.x - bv.x; xs[tid * 4 + 1] = xv.y - bv.y;
        xs[tid * 4 + 2] = xv.z - bv.z; xs[tid * 4 + 3] = xv.w - bv.w;
    }
    __syncthreads();

    // coalesced exact-f32 recompute: 4 threads/feature, 64 features/pass
    int fg = tid >> 2, sub = tid & 3;
    for (int pass = 0; pass < D_SAE / 64; ++pass) {
        int f = pass * 64 + fg;
        const float* wr = wt + (size_t)f * D_VIT;
        float a = 0.f;
        for (int j = 0; j < 48; ++j) {
            int k = sub * 4 + j * 16;
            float4 wv = *reinterpret_cast<const float4*>(wr + k);
            float4 xv = *reinterpret_cast<const float4*>(xs + k);
            a = fmaf(wv.x, xv.x, a); a = fmaf(wv.y, xv.y, a);
            a = fmaf(wv.z, xv.z, a); a = fmaf(wv.w, xv.w, a);
        }
        a += __shfl_xor(a, 1); a += __shfl_xor(a, 2);
        if (sub == 0) {
            union { __hip_bfloat16 h; unsigned short u; } cc;
            cc.h = __float2bfloat16(fmaxf(a, 0.f));
            actl[f] = cc.u;
        }
    }
    __syncthreads();

    // two-level histogram threshold for top-NCF superset (codes from LDS)
    for (int i = tid; i < D_SAE; i += 256) {
        unsigned c = actl[i];
        if (c && c < 0x8000u) atomicAdd(&hist1[c >> 7], 1u);
    }
    __syncthreads();
    if (tid < 64) {
        int l = tid;
        unsigned c0 = hist1[4 * l], c1 = hist1[4 * l + 1],
                 c2 = hist1[4 * l + 2], c3 = hist1[4 * l + 3];
        unsigned S = c0 + c1 + c2 + c3;
#pragma unroll
        for (int o = 1; o < 64; o <<= 1) {
            unsigned t = __shfl_down(S, o);
            if (l + o < 64) S += t;
        }
        unsigned above = __shfl_down(S, 1);
        if (l == 63) above = 0;
        if (S >= NCF && above < NCF) {
            int b1; unsigned ab;
            if (above + c3 >= NCF)                { b1 = 4 * l + 3; ab = above; }
            else if (above + c3 + c2 >= NCF)      { b1 = 4 * l + 2; ab = above + c3; }
            else if (above + c3 + c2 + c1 >= NCF) { b1 = 4 * l + 1; ab = above + c3 + c2; }
            else                                  { b1 = 4 * l;     ab = above + c3 + c2 + c1; }
            s_b1 = b1; s_above = ab;
        }
    }
    __syncthreads();
    int b1 = s_b1;
    if (b1 >= 0) {
        for (int i = tid; i < D_SAE; i += 256) {
            unsigned c = actl[i];
            if (c && c < 0x8000u && (int)(c >> 7) == b1) atomicAdd(&hist2[c & 127u], 1u);
        }
        __syncthreads();
        if (tid < 64) {
            int l = tid;
            unsigned above0 = s_above;
            unsigned c0 = hist2[2 * l], c1 = hist2[2 * l + 1];
            unsigned S = c0 + c1;
#pragma unroll
            for (int o = 1; o < 64; o <<= 1) {
                unsigned t = __shfl_down(S, o);
                if (l + o < 64) S += t;
            }
            unsigned ab2 = __shfl_down(S, 1);
            if (l == 63) ab2 = 0;
            if (above0 + S >= NCF && above0 + ab2 < NCF) {
                if (above0 + ab2 + c1 >= NCF) s_code = (b1 << 7) | (2 * l + 1);
                else                          s_code = (b1 << 7) | (2 * l);
            }
        }
        __syncthreads();
    }
    int code = s_code;

    for (int i = tid; i < D_SAE; i += 256) {
        unsigned c = actl[i];
        if (c < 0x8000u && (int)c >= code) {
            int slot = atomicAdd(&s_cnt, 1);
            if (slot < CFB) cand[slot] = i;
        }
    }
    __syncthreads();
    int C = s_cnt < CFB ? s_cnt : CFB;

    // f64 rerank all candidates
    for (int base = 0; base < C; base += 64) {
        int ai = base + (tid >> 2), sb = tid & 3;
        if (ai < C) {
            const float* wr = wt + (size_t)cand[ai] * D_VIT;
            double a = 0.0;
            for (int k = sb * 4; k < D_VIT; k += 16) {
                float4 wv = *reinterpret_cast<const float4*>(wr + k);
                float4 xv = *reinterpret_cast<const float4*>(xs + k);
                a += (double)wv.x * xv.x + (double)wv.y * xv.y
                   + (double)wv.z * xv.z + (double)wv.w * xv.w;
            }
            a += __shfl_xor(a, 1); a += __shfl_xor(a, 2);
            if (sb == 0) cval[ai] = a > 0.0 ? a : 0.0;
        }
    }
    __syncthreads();

    // exact top-32 routing (content-based)
    for (int c = tid; c < C; c += 256) {
        double mv = cval[c]; int mi = cand[c]; int rk = 0;
        for (int j = 0; j < C; ++j) {
            double vj = cval[j]; int ij = cand[j];
            rk += (vj > mv) || (vj == mv && ij < mi);
        }
        if (rk < TOPK) { sval[rk] = (float)mv; sidx[rk] = mi; }
    }
    __syncthreads();

    if (tid < 192) {
        int d0 = tid * 4;
        float4 o = *reinterpret_cast<const float4*>(bdec + d0);
#pragma unroll
        for (int j = 0; j < TOPK; ++j) {
            float s = sval[j];
            uint2 u = *reinterpret_cast<const uint2*>(wdecb + (size_t)sidx[j] * D_VIT + d0);
            o.x = fmaf(s, __uint_as_float(u.x << 16), o.x);
            o.y = fmaf(s, __uint_as_float(u.x & 0xffff0000u), o.y);
            o.z = fmaf(s, __uint_as_float(u.y << 16), o.z);
            o.w = fmaf(s, __uint_as_float(u.y & 0xffff0000u), o.w);
        }
        *reinterpret_cast<float4*>(out + (size_t)row * D_VIT + d0) = o;
    }
}

extern "C" void kernel_launch(void* const* d_in, const int* in_sizes, int n_in,
                              void* d_out, int out_size, void* d_ws, size_t ws_size,
                              hipStream_t stream) {
    const float* x    = (const float*)d_in[0];
    const float* wenc = (const float*)d_in[1];
    const float* wdec = (const float*)d_in[2];
    const float* bdec = (const float*)d_in[3];
    float* out = (float*)d_out;
    int M = in_sizes[0] / D_VIT;

    size_t wt_b    = (size_t)D_SAE * D_VIT * sizeof(float);
    size_t wtb_b   = (size_t)D_SAE * D_VIT * sizeof(__hip_bfloat16);
    size_t xb_b    = (size_t)M * D_VIT * sizeof(__hip_bfloat16);
    size_t wdecb_b = (size_t)D_SAE * D_VIT * sizeof(__hip_bfloat16);
    size_t cnt_b   = (size_t)M * sizeof(int);
    size_t flag_b  = (size_t)M * sizeof(int);

    char* p = (char*)d_ws;
    float* wt             = (float*)p;              p += wt_b;
    __hip_bfloat16* wtb   = (__hip_bfloat16*)p;     p += wtb_b;
    __hip_bfloat16* xb    = (__hip_bfloat16*)p;     p += xb_b;
    __hip_bfloat16* wdecb = (__hip_bfloat16*)p;     p += wdecb_b;
    int* cnt              = (int*)p;                p += cnt_b;
    int* fflag            = (int*)p;                p += flag_b;
    int* candb            = (int*)p;

    {
        int blocks = (M + 255) / 256;
        hipLaunchKernelGGL(k_zero, dim3(blocks), dim3(256), 0, stream, cnt, fflag, M);
    }
    {
        dim3 g(D_SAE / 32, D_VIT / 32), b(32, 8);
        hipLaunchKernelGGL(k_transpose, g, b, 0, stream, wenc, wt, wtb);
    }
    {
        long long n = (long long)M * D_VIT;
        int blocks = (int)((n / 8 + 255) / 256);
        hipLaunchKernelGGL(k_cvt_x, dim3(blocks), dim3(256), 0, stream, x, bdec, xb, n);
    }
    {
        long long n = (long long)D_SAE * D_VIT;
        int blocks = (int)((n / 8 + 255) / 256);
        hipLaunchKernelGGL(k_cvt_w, dim3(blocks), dim3(256), 0, stream, wdec, wdecb, n);
    }
    {
        dim3 ge(D_SAE / GBN, (M + GBM - 1) / GBM), be(512);
        hipLaunchKernelGGL(k_enc8, ge, be, 0, stream, xb, wtb, cnt, candb, M);
    }
    hipLaunchKernelGGL(k_select, dim3(M), dim3(256), 0, stream,
                       cnt, candb, x, bdec, wt, wdecb, out, fflag);
    hipLaunchKernelGGL(k_fallback, dim3(M), dim3(256), 0, stream,
                       fflag, x, bdec, wt, wdecb, out);
}